// Round 1
// baseline (202.528 us; speedup 1.0000x reference)
//
#include <hip/hip_runtime.h>
#include <math.h>

#pragma clang fp contract(off)

constexpr int cBS = 32, cNA = 5, cNY = 52, cNX = 52, cNC = 80, cM = 50;
constexpr int cS  = cNY * cNX;   // 2704
constexpr int cCH = 5 + cNC;     // 85
constexpr int cOC = 10;          // iou_t(1) iou_m(1) box_t(4) box_m(1) box_s(1) cls_t(1) cls_m(1)

// XLA/Eigen f32 tanh rational approximation (matches XLA's EmitTanh for F32).
__device__ __forceinline__ float xla_tanh(float x) {
    const float kMax = 7.90531110763549805f;
    float xc = fminf(fmaxf(x, -kMax), kMax);
    float x2 = xc * xc;
    float num = fmaf(x2, -2.76076847742355e-16f, 2.00018790482477e-13f);
    num = fmaf(x2, num, -8.60467152213735e-11f);
    num = fmaf(x2, num, 5.12229709037114e-08f);
    num = fmaf(x2, num, 1.48572235717979e-05f);
    num = fmaf(x2, num, 6.37261928875436e-04f);
    num = fmaf(x2, num, 4.89352455891786e-03f);
    num = xc * num;
    float den = fmaf(x2, 1.19825839466702e-06f, 1.18534705686654e-04f);
    den = fmaf(x2, den, 2.26843463243900e-03f);
    den = fmaf(x2, den, 4.89352518554385e-03f);
    float r = num / den;
    return (fabsf(x) < 0.0004f) ? x : r;
}

// XLA logistic expansion: 0.5 + 0.5 * tanh(0.5 * x)
__device__ __forceinline__ float xla_sigmoid(float x) {
    return 0.5f + 0.5f * xla_tanh(0.5f * x);
}

__global__ __launch_bounds__(256) void yolo_loss_kernel(
    const float* __restrict__ preds,     // (BS,NA,NY,NX,85)
    const float* __restrict__ gt_boxes,  // (BS,M,4)
    const int*   __restrict__ gt_cls,    // (BS,M)
    const int*   __restrict__ gt_valid,  // (BS,M)
    const float* __restrict__ anchors,   // (NA,2)
    float* __restrict__ out)             // (BS,NA,S,10)
{
    // per-valid-gt record (compacted, m-order preserved):
    // [0..3] gt xyxy  [4] areaB  [5] key bits ((astar<<12)|cell)
    // [6] dx  [7] dy  [8] gw  [9] gh  [10] cls  [11] pad
    __shared__ __align__(16) float rec[cM][12];
    __shared__ int s_nv;

    const int b   = blockIdx.y;
    const int tid = threadIdx.x;

    // ---------- staging: wave 0 processes the 50 gts of batch b ----------
    if (tid < 64) {
        bool valid = false;
        float x1 = 0.f, y1 = 0.f, x2 = 0.f, y2 = 0.f, areaB = 0.f;
        float dx = 0.f, dy = 0.f, gw = 0.f, gh = 0.f, clsf = 0.f;
        int key = 0;
        if (tid < cM) {
            const int m = tid;
            valid = gt_valid[b * cM + m] > 0;
            float4 gb = *reinterpret_cast<const float4*>(&gt_boxes[(b * cM + m) * 4]);
            float gx = gb.x * 52.0f, gy = gb.y * 52.0f;
            gw = gb.z * 52.0f; gh = gb.w * 52.0f;
            x1 = gx - gw * 0.5f; y1 = gy - gh * 0.5f;
            x2 = gx + gw * 0.5f; y2 = gy + gh * 0.5f;
            areaB = (x2 - x1) * (y2 - y1);
            int cix = (int)fminf(fmaxf(floorf(gx), 0.0f), 51.0f);
            int ciy = (int)fminf(fmaxf(floorf(gy), 0.0f), 51.0f);
            int cell = ciy * 52 + cix;
            // argmax over the 5 anchor-box IoUs at this cell (first max wins)
            float acx = (float)cix, acy = (float)ciy;
            float best = -1e30f; int astar = 0;
#pragma unroll
            for (int a = 0; a < 5; ++a) {
                float aw = anchors[2 * a], ah = anchors[2 * a + 1];
                float ax1 = acx - aw * 0.5f, ay1 = acy - ah * 0.5f;
                float ax2 = acx + aw * 0.5f, ay2 = acy + ah * 0.5f;
                float ltx = fmaxf(ax1, x1), lty = fmaxf(ay1, y1);
                float rbx = fminf(ax2, x2), rby = fminf(ay2, y2);
                float w = fmaxf(rbx - ltx, 0.0f), h = fmaxf(rby - lty, 0.0f);
                float inter = w * h;
                float areaA = (ax2 - ax1) * (ay2 - ay1);
                float u = areaA + areaB - inter + 1e-9f;
                float ov = inter / u;
                if (ov > best) { best = ov; astar = a; }
            }
            key = (astar << 12) | cell;
            dx = gx - (float)cix;
            dy = gy - (float)ciy;
            clsf = (float)gt_cls[b * cM + m];
        }
        unsigned long long bal = __ballot(valid);
        int pos = __popcll(bal & ((1ull << tid) - 1ull));
        if (valid) {
            rec[pos][0] = x1; rec[pos][1] = y1; rec[pos][2] = x2; rec[pos][3] = y2;
            rec[pos][4] = areaB;
            rec[pos][5] = __int_as_float(key);
            rec[pos][6] = dx; rec[pos][7] = dy;
            rec[pos][8] = gw; rec[pos][9] = gh;
            rec[pos][10] = clsf;
        }
        if (tid == 0) s_nv = __popcll(bal);
    }
    __syncthreads();

    // ---------- main: one thread per (a, s) output location ----------
    const int flat = blockIdx.x * 256 + tid;   // a*S + s
    if (flat >= cNA * cS) return;
    const int a = flat / cS;
    const int s = flat - a * cS;
    const int gxi = s % cNX, gyi = s / cNX;

    const float* p = preds + ((size_t)((b * cNA + a) * cS + s)) * cCH;
    float t0 = p[0], t1 = p[1], t2 = p[2], t3 = p[3];
    float aw = anchors[2 * a], ah = anchors[2 * a + 1];
    float px = xla_sigmoid(t0) + (float)gxi;
    float py = xla_sigmoid(t1) + (float)gyi;
    float pw = expf(t2) * aw;
    float ph = expf(t3) * ah;
    float bx1 = px - pw * 0.5f, by1 = py - ph * 0.5f;
    float bx2 = px + pw * 0.5f, by2 = py + ph * 0.5f;
    float areaA = (bx2 - bx1) * (by2 - by1);
    const int mykey = (a << 12) | s;

    // division-free running max via (num, den) cross-multiplication
    float bnum = -1.0f, bden = 1.0f;
    int winner = -1;
    const int nv = s_nv;
    for (int i = 0; i < nv; ++i) {
        float4 box = *reinterpret_cast<const float4*>(&rec[i][0]);
        float areaB = rec[i][4];
        int key = __float_as_int(rec[i][5]);
        float ltx = fmaxf(bx1, box.x), lty = fmaxf(by1, box.y);
        float rbx = fminf(bx2, box.z), rby = fminf(by2, box.w);
        float w = fmaxf(rbx - ltx, 0.0f), h = fmaxf(rby - lty, 0.0f);
        float inter = w * h;
        float u = areaA + areaB - inter + 1e-9f;
        bool upd = inter * bden > bnum * u;         // inter/u > bnum/bden
        bnum = upd ? inter : bnum;
        bden = upd ? u : bden;
        winner = (key == mykey) ? i : winner;       // last valid m wins
    }

    float d = bnum / bden;   // == reference max_iou (monotone rounding)
    float mask = (bnum >= 0.0f && d < 0.5f) ? 1.0f : 0.0f;

    float o0 = 0.f, o1 = mask, o2 = 0.f, o3 = 0.f, o4 = 0.f;
    float o5 = 0.f, o6 = 0.f, o7 = 0.f, o8 = 0.f, o9 = 0.f;
    if (winner >= 0) {
        float dx = rec[winner][6], dy = rec[winner][7];
        float gw = rec[winner][8], gh = rec[winner][9];
        float clsf = rec[winner][10];
        o0 = d;                                      // iou_target = mi
        o1 = 2.0f;                                   // iou_mask scatter
        o2 = dx; o3 = dy;
        o4 = gw / aw; o5 = gh / ah;                  // box_target w,h
        o6 = 1.0f;                                   // box_mask
        o7 = 2.0f - (pw / 52.0f) * (ph / 52.0f);     // box_scale
        o8 = clsf;                                   // class_target
        o9 = 1.0f;                                   // class_mask
    }

    float* op = out + (size_t)((b * cNA + a) * cS + s) * cOC;
    float2* op2 = reinterpret_cast<float2*>(op);
    op2[0] = make_float2(o0, o1);
    op2[1] = make_float2(o2, o3);
    op2[2] = make_float2(o4, o5);
    op2[3] = make_float2(o6, o7);
    op2[4] = make_float2(o8, o9);
}

extern "C" void kernel_launch(void* const* d_in, const int* in_sizes, int n_in,
                              void* d_out, int out_size, void* d_ws, size_t ws_size,
                              hipStream_t stream) {
    const float* preds    = (const float*)d_in[0];
    const float* gt_boxes = (const float*)d_in[1];
    const int*   gt_cls   = (const int*)d_in[2];
    const int*   gt_valid = (const int*)d_in[3];
    const float* anchors  = (const float*)d_in[4];
    float* out = (float*)d_out;

    dim3 grid((cNA * cS + 255) / 256, cBS);   // 53 x 32 blocks
    yolo_loss_kernel<<<grid, dim3(256), 0, stream>>>(
        preds, gt_boxes, gt_cls, gt_valid, anchors, out);
}

// Round 3
// 197.402 us; speedup vs baseline: 1.0260x; 1.0260x over previous
//
#include <hip/hip_runtime.h>
#include <math.h>

#pragma clang fp contract(off)

constexpr int cBS = 32, cNA = 5, cNY = 52, cNX = 52, cNC = 80, cM = 50;
constexpr int cS  = cNY * cNX;   // 2704
constexpr int cCH = 5 + cNC;     // 85
constexpr int cOC = 10;          // iou_t(1) iou_m(1) box_t(4) box_m(1) box_s(1) cls_t(1) cls_m(1)
constexpr int cBLK = 512;

typedef float v2f __attribute__((ext_vector_type(2)));

// XLA/Eigen f32 tanh rational approximation (matches XLA's EmitTanh for F32).
__device__ __forceinline__ float xla_tanh(float x) {
    const float kMax = 7.90531110763549805f;
    float xc = fminf(fmaxf(x, -kMax), kMax);
    float x2 = xc * xc;
    float num = fmaf(x2, -2.76076847742355e-16f, 2.00018790482477e-13f);
    num = fmaf(x2, num, -8.60467152213735e-11f);
    num = fmaf(x2, num, 5.12229709037114e-08f);
    num = fmaf(x2, num, 1.48572235717979e-05f);
    num = fmaf(x2, num, 6.37261928875436e-04f);
    num = fmaf(x2, num, 4.89352455891786e-03f);
    num = xc * num;
    float den = fmaf(x2, 1.19825839466702e-06f, 1.18534705686654e-04f);
    den = fmaf(x2, den, 2.26843463243900e-03f);
    den = fmaf(x2, den, 4.89352518554385e-03f);
    float r = num / den;
    return (fabsf(x) < 0.0004f) ? x : r;
}

// XLA logistic expansion: 0.5 + 0.5 * tanh(0.5 * x)
__device__ __forceinline__ float xla_sigmoid(float x) {
    return 0.5f + 0.5f * xla_tanh(0.5f * x);
}

__global__ __launch_bounds__(cBLK) void yolo_loss_kernel(
    const float* __restrict__ preds,     // (BS,NA,NY,NX,85)
    const float* __restrict__ gt_boxes,  // (BS,M,4)
    const int*   __restrict__ gt_cls,    // (BS,M)
    const int*   __restrict__ gt_valid,  // (BS,M)
    const float* __restrict__ anchors,   // (NA,2)
    float* __restrict__ out)             // (BS,NA,S,10)
{
    // per-valid-gt record (compacted, m-order preserved):
    // [0..3] gt xyxy  [4] areaB  [5] key bits ((astar<<12)|cell)
    // [6] dx  [7] dy  [8] gw  [9] gh  [10] cls  [11] pad
    __shared__ __align__(16) float rec[cM][12];
    __shared__ int s_nv;

    const int b   = blockIdx.y;
    const int tid = threadIdx.x;

    // ---------- hoisted main-thread loads: overlap global latency with staging ----------
    const int flat = blockIdx.x * cBLK + tid;   // a*S + s
    const bool active = flat < cNA * cS;
    int a = 0, s = 0;
    float t0 = 0.f, t1 = 0.f, t2 = 0.f, t3 = 0.f;
    float aw = 0.f, ah = 0.f;
    if (active) {
        a = flat / cS;
        s = flat - a * cS;
        const float* p = preds + ((size_t)((b * cNA + a) * cS + s)) * cCH;
        t0 = __builtin_nontemporal_load(p + 0);
        t1 = __builtin_nontemporal_load(p + 1);
        t2 = __builtin_nontemporal_load(p + 2);
        t3 = __builtin_nontemporal_load(p + 3);
        aw = anchors[2 * a];
        ah = anchors[2 * a + 1];
    }

    // ---------- staging: wave 0 processes the 50 gts of batch b ----------
    if (tid < 64) {
        bool valid = false;
        float x1 = 0.f, y1 = 0.f, x2 = 0.f, y2 = 0.f, areaB = 0.f;
        float dx = 0.f, dy = 0.f, gw = 0.f, gh = 0.f, clsf = 0.f;
        int key = 0;
        if (tid < cM) {
            const int m = tid;
            valid = gt_valid[b * cM + m] > 0;
            float4 gb = *reinterpret_cast<const float4*>(&gt_boxes[(b * cM + m) * 4]);
            float gx = gb.x * 52.0f, gy = gb.y * 52.0f;
            gw = gb.z * 52.0f; gh = gb.w * 52.0f;
            x1 = gx - gw * 0.5f; y1 = gy - gh * 0.5f;
            x2 = gx + gw * 0.5f; y2 = gy + gh * 0.5f;
            areaB = (x2 - x1) * (y2 - y1);
            int cix = (int)fminf(fmaxf(floorf(gx), 0.0f), 51.0f);
            int ciy = (int)fminf(fmaxf(floorf(gy), 0.0f), 51.0f);
            int cell = ciy * 52 + cix;
            // argmax over the 5 anchor-box IoUs at this cell (first max wins)
            float acx = (float)cix, acy = (float)ciy;
            float best = -1e30f; int astar = 0;
#pragma unroll
            for (int aa = 0; aa < 5; ++aa) {
                float aw_ = anchors[2 * aa], ah_ = anchors[2 * aa + 1];
                float ax1 = acx - aw_ * 0.5f, ay1 = acy - ah_ * 0.5f;
                float ax2 = acx + aw_ * 0.5f, ay2 = acy + ah_ * 0.5f;
                float ltx = fmaxf(ax1, x1), lty = fmaxf(ay1, y1);
                float rbx = fminf(ax2, x2), rby = fminf(ay2, y2);
                float w = fmaxf(rbx - ltx, 0.0f), h = fmaxf(rby - lty, 0.0f);
                float inter = w * h;
                float areaA = (ax2 - ax1) * (ay2 - ay1);
                float u = areaA + areaB - inter + 1e-9f;
                float ov = inter / u;
                if (ov > best) { best = ov; astar = aa; }
            }
            key = (astar << 12) | cell;
            dx = gx - (float)cix;
            dy = gy - (float)ciy;
            clsf = (float)gt_cls[b * cM + m];
        }
        unsigned long long bal = __ballot(valid);
        int pos = __popcll(bal & ((1ull << tid) - 1ull));
        if (valid) {
            rec[pos][0] = x1; rec[pos][1] = y1; rec[pos][2] = x2; rec[pos][3] = y2;
            rec[pos][4] = areaB;
            rec[pos][5] = __int_as_float(key);
            rec[pos][6] = dx; rec[pos][7] = dy;
            rec[pos][8] = gw; rec[pos][9] = gh;
            rec[pos][10] = clsf;
        }
        if (tid == 0) s_nv = __popcll(bal);
    }
    __syncthreads();

    // ---------- main: one thread per (a, s) output location ----------
    if (!active) return;
    const int gxi = s % cNX, gyi = s / cNX;

    float px = xla_sigmoid(t0) + (float)gxi;
    float py = xla_sigmoid(t1) + (float)gyi;
    float pw = expf(t2) * aw;
    float ph = expf(t3) * ah;
    float bx1 = px - pw * 0.5f, by1 = py - ph * 0.5f;
    float bx2 = px + pw * 0.5f, by2 = py + ph * 0.5f;
    float areaA = (bx2 - bx1) * (by2 - by1);
    const int mykey = (a << 12) | s;

    // division-free running max via (num, den) cross-multiplication
    float bnum = -1.0f, bden = 1.0f;
    int winner = -1;
    const int nv = s_nv;
#pragma unroll 2
    for (int i = 0; i < nv; ++i) {
        float4 box = *reinterpret_cast<const float4*>(&rec[i][0]);
        float areaB = rec[i][4];
        int key = __float_as_int(rec[i][5]);
        float ltx = fmaxf(bx1, box.x), lty = fmaxf(by1, box.y);
        float rbx = fminf(bx2, box.z), rby = fminf(by2, box.w);
        float w = fmaxf(rbx - ltx, 0.0f), h = fmaxf(rby - lty, 0.0f);
        float inter = w * h;
        float u = areaA + areaB - inter + 1e-9f;
        bool upd = inter * bden > bnum * u;         // inter/u > bnum/bden
        bnum = upd ? inter : bnum;
        bden = upd ? u : bden;
        winner = (key == mykey) ? i : winner;       // last valid m wins
    }

    float d = bnum / bden;   // == reference max_iou (monotone rounding)
    float mask = (bnum >= 0.0f && d < 0.5f) ? 1.0f : 0.0f;

    float o0 = 0.f, o1 = mask, o2 = 0.f, o3 = 0.f, o4 = 0.f;
    float o5 = 0.f, o6 = 0.f, o7 = 0.f, o8 = 0.f, o9 = 0.f;
    if (winner >= 0) {
        float dx = rec[winner][6], dy = rec[winner][7];
        float gw = rec[winner][8], gh = rec[winner][9];
        float clsf = rec[winner][10];
        o0 = d;                                      // iou_target = mi
        o1 = 2.0f;                                   // iou_mask scatter
        o2 = dx; o3 = dy;
        o4 = gw / aw; o5 = gh / ah;                  // box_target w,h
        o6 = 1.0f;                                   // box_mask
        o7 = 2.0f - (pw / 52.0f) * (ph / 52.0f);     // box_scale
        o8 = clsf;                                   // class_target
        o9 = 1.0f;                                   // class_mask
    }

    float* op = out + (size_t)((b * cNA + a) * cS + s) * cOC;
    v2f* op2 = reinterpret_cast<v2f*>(op);
    __builtin_nontemporal_store((v2f){o0, o1}, op2 + 0);
    __builtin_nontemporal_store((v2f){o2, o3}, op2 + 1);
    __builtin_nontemporal_store((v2f){o4, o5}, op2 + 2);
    __builtin_nontemporal_store((v2f){o6, o7}, op2 + 3);
    __builtin_nontemporal_store((v2f){o8, o9}, op2 + 4);
}

extern "C" void kernel_launch(void* const* d_in, const int* in_sizes, int n_in,
                              void* d_out, int out_size, void* d_ws, size_t ws_size,
                              hipStream_t stream) {
    const float* preds    = (const float*)d_in[0];
    const float* gt_boxes = (const float*)d_in[1];
    const int*   gt_cls   = (const int*)d_in[2];
    const int*   gt_valid = (const int*)d_in[3];
    const float* anchors  = (const float*)d_in[4];
    float* out = (float*)d_out;

    dim3 grid((cNA * cS + cBLK - 1) / cBLK, cBS);   // 27 x 32 blocks
    yolo_loss_kernel<<<grid, dim3(cBLK), 0, stream>>>(
        preds, gt_boxes, gt_cls, gt_valid, anchors, out);
}